// Round 5
// baseline (142.842 us; speedup 1.0000x reference)
//
#include <hip/hip_runtime.h>

#define NS 1024
#define KD 256
#define H  256
#define PAIR_NBLK 512

#define GLOAD_LDS16(gp, lp)                                                         \
    __builtin_amdgcn_global_load_lds(                                               \
        (const __attribute__((address_space(1))) void*)(gp),                        \
        (__attribute__((address_space(3))) void*)(lp), 16, 0, 0)

// ---------------------------------------------------------------------------
// proj: PXT[h][j] = x_j . W1[:,h]   (transposed output, coalesced)
//       PYT[h][i] = y_i . W1[256+,h] + b1[h]
//       FX[j] = sum_h w2[h]*PXT[h][j],  GY[i] = sum_h w2[h]*PYT[h][i]
// grid (8 h-slices of 32, 32 sample-slices of 32, 2), block 256.
// thread: jl = tid&31 (sample), hg = tid>>5 (8 groups x 4 h).
// ---------------------------------------------------------------------------
__global__ __launch_bounds__(256) void proj_kernel(
    const float* __restrict__ X, const float* __restrict__ Y,
    const float* __restrict__ W1, const float* __restrict__ b1,
    const float* __restrict__ W2,
    float* __restrict__ PXT, float* __restrict__ PYT,
    float* __restrict__ FX, float* __restrict__ GY)
{
    const int z = blockIdx.z;
    const float* __restrict__ A = z ? Y : X;
    const float* __restrict__ W = W1 + (z ? (size_t)KD * H : 0);
    float* __restrict__ OUT = z ? PYT : PXT;
    float* __restrict__ RS  = z ? GY : FX;

    __shared__ float xs[KD][34];    // transposed [k][sample-local]
    __shared__ float fred[8][33];

    const int tid = threadIdx.x;
    const int jl = tid & 31;        // sample within block
    const int hg = tid >> 5;        // 0..7, 4 h's each
    const int i0 = blockIdx.y * 32, h0 = blockIdx.x * 32;

    // stage A rows transposed (32 rows x 256 k), once
    {
        const int ii = tid & 31, q = tid >> 5;
        #pragma unroll
        for (int u = 0; u < 8; ++u) {
            const int k = u * 32 + q * 4;
            float4 v = *(const float4*)&A[(i0 + ii) * KD + k];
            xs[k + 0][ii] = v.x; xs[k + 1][ii] = v.y;
            xs[k + 2][ii] = v.z; xs[k + 3][ii] = v.w;
        }
    }
    __syncthreads();

    float acc[4] = {};
    const float* __restrict__ wp = &W[h0 + hg * 4];
    #pragma unroll 8
    for (int k = 0; k < KD; ++k) {
        float4 w4 = *(const float4*)&wp[(size_t)k * H];
        const float xv = xs[k][jl];
        acc[0] = fmaf(xv, w4.x, acc[0]);
        acc[1] = fmaf(xv, w4.y, acc[1]);
        acc[2] = fmaf(xv, w4.z, acc[2]);
        acc[3] = fmaf(xv, w4.w, acc[3]);
    }

    if (z) {
        float4 bv = *(const float4*)&b1[h0 + hg * 4];
        acc[0] += bv.x; acc[1] += bv.y; acc[2] += bv.z; acc[3] += bv.w;
    }

    float4 w2v = *(const float4*)&W2[h0 + hg * 4];
    float fp = 0.f;
    const float w2a[4] = {w2v.x, w2v.y, w2v.z, w2v.w};
    #pragma unroll
    for (int c = 0; c < 4; ++c) {
        const int h = h0 + hg * 4 + c;
        OUT[(size_t)h * NS + i0 + jl] = acc[c];   // coalesced: 32 consecutive j
        fp = fmaf(w2a[c], acc[c], fp);
    }
    fred[hg][jl] = fp;
    __syncthreads();
    if (tid < 32) {
        float s = 0.f;
        #pragma unroll
        for (int g = 0; g < 8; ++g) s += fred[g][tid];
        atomicAdd(&RS[i0 + tid], s);
    }
}

// ---------------------------------------------------------------------------
// pair: tile 128 j x 16 i, grid (8,64)=512 blocks (2 blocks/CU, 2 waves/SIMD).
// wave w owns rows i0+4w..+3 (py via uniform-addr float4 broadcast from PYT),
// lane owns 2 j's (px via LDS b64, staged by async global_load_lds, dbuf).
// inner: u = py+px; acc = fma(|u|, w2, acc)  -> 2 VALU ops per cell-h.
// t1 = 0.5*(acc + FX_j + GY_i) + b2 - 1. exp-sum + diagonal; last block
// finalizes out.
// ---------------------------------------------------------------------------
__global__ __launch_bounds__(256) void pair_kernel(
    const float* __restrict__ PXT, const float* __restrict__ PYT,
    const float* __restrict__ W2, const float* __restrict__ b2,
    const float* __restrict__ FX, const float* __restrict__ GY,
    float* __restrict__ eparts, float* __restrict__ dparts,
    int* __restrict__ counter, float* __restrict__ out)
{
    __shared__ float pxs[2][32][128];   // [buf][h][j] 32 KB
    __shared__ float red_e[256], red_d[256];
    __shared__ double sde[256], sdd[256];
    __shared__ int lastflag;

    const int tid = threadIdx.x;
    const int lane = tid & 63;
    const int wid = __builtin_amdgcn_readfirstlane(tid >> 6);
    const int j0 = blockIdx.x * 128;
    const int i0 = blockIdx.y * 16;

#define STAGE(T, B)                                                             \
    {                                                                           \
        const float* gb = &PXT[(size_t)((T) * 32) * NS + j0];                   \
        _Pragma("unroll")                                                       \
        for (int p = 0; p < 4; ++p) {                                           \
            const int hrow = 8 * p + 2 * wid + (lane >> 5);                     \
            const float* g = gb + (size_t)hrow * NS + (lane & 31) * 4;          \
            float* l = &pxs[B][hrow][(lane & 31) * 4];                          \
            GLOAD_LDS16(g, l);                                                  \
        }                                                                       \
    }

    STAGE(0, 0);
    __syncthreads();

    float acc[4][2] = {};
    const float* __restrict__ pyb = &PYT[i0 + wid * 4];

    for (int T = 0; T < 8; ++T) {
        const int B = T & 1;
        if (T < 7) STAGE(T + 1, B ^ 1);   // async; drained by end barrier
        #pragma unroll
        for (int g = 0; g < 8; ++g) {
            float4 w4 = *(const float4*)&W2[T * 32 + g * 4];
            const float wa[4] = {w4.x, w4.y, w4.z, w4.w};
            #pragma unroll
            for (int k = 0; k < 4; ++k) {
                const int hh = g * 4 + k;
                float2 px2 = *(const float2*)&pxs[B][hh][lane * 2];
                float4 p4 = *(const float4*)&pyb[(size_t)(T * 32 + hh) * NS];
                const float pya[4] = {p4.x, p4.y, p4.z, p4.w};
                #pragma unroll
                for (int r = 0; r < 4; ++r) {
                    acc[r][0] = fmaf(fabsf(pya[r] + px2.x), wa[k], acc[r][0]);
                    acc[r][1] = fmaf(fabsf(pya[r] + px2.y), wa[k], acc[r][1]);
                }
            }
        }
        __syncthreads();
    }

    // epilogue
    const float c0 = b2[0] - 1.0f;
    float2 fx2 = *(const float2*)&FX[j0 + lane * 2];
    float4 g4 = *(const float4*)&GY[i0 + wid * 4];
    const float gya[4] = {g4.x, g4.y, g4.z, g4.w};
    const float fxa[2] = {fx2.x, fx2.y};

    float esum = 0.f, dsum = 0.f;
    #pragma unroll
    for (int r = 0; r < 4; ++r) {
        const int irow = i0 + wid * 4 + r;
        #pragma unroll
        for (int c = 0; c < 2; ++c) {
            const float t1 = fmaf(0.5f, acc[r][c] + gya[r] + fxa[c], c0);
            esum += expf(t1);
            if (irow == j0 + lane * 2 + c) dsum += t1 + 1.0f;
        }
    }

    red_e[tid] = esum;
    red_d[tid] = dsum;
    __syncthreads();
    for (int s = 128; s > 0; s >>= 1) {
        if (tid < s) {
            red_e[tid] += red_e[tid + s];
            red_d[tid] += red_d[tid + s];
        }
        __syncthreads();
    }

    const int bid = blockIdx.y * gridDim.x + blockIdx.x;   // 0..511
    if (tid == 0) {
        __hip_atomic_store(&eparts[bid], red_e[0], __ATOMIC_RELAXED, __HIP_MEMORY_SCOPE_AGENT);
        __hip_atomic_store(&dparts[bid], red_d[0], __ATOMIC_RELAXED, __HIP_MEMORY_SCOPE_AGENT);
        __threadfence();
        const int prev = __hip_atomic_fetch_add(counter, 1, __ATOMIC_ACQ_REL, __HIP_MEMORY_SCOPE_AGENT);
        lastflag = (prev == PAIR_NBLK - 1);
    }
    __syncthreads();

    if (lastflag) {
        __threadfence();
        sde[tid] = (double)__hip_atomic_load(&eparts[tid], __ATOMIC_RELAXED, __HIP_MEMORY_SCOPE_AGENT)
                 + (double)__hip_atomic_load(&eparts[tid + 256], __ATOMIC_RELAXED, __HIP_MEMORY_SCOPE_AGENT);
        sdd[tid] = (double)__hip_atomic_load(&dparts[tid], __ATOMIC_RELAXED, __HIP_MEMORY_SCOPE_AGENT)
                 + (double)__hip_atomic_load(&dparts[tid + 256], __ATOMIC_RELAXED, __HIP_MEMORY_SCOPE_AGENT);
        __syncthreads();
        for (int s = 128; s > 0; s >>= 1) {
            if (tid < s) { sde[tid] += sde[tid + s]; sdd[tid] += sdd[tid + s]; }
            __syncthreads();
        }
        if (tid == 0)
            out[0] = (float)(sdd[0] / (double)NS - sde[0] / ((double)NS * (double)NS));
    }
#undef STAGE
}

// ---------------------------------------------------------------------------
extern "C" void kernel_launch(void* const* d_in, const int* in_sizes, int n_in,
                              void* d_out, int out_size, void* d_ws, size_t ws_size,
                              hipStream_t stream)
{
    const float* X  = (const float*)d_in[0];
    const float* Y  = (const float*)d_in[1];
    const float* W1 = (const float*)d_in[2];
    const float* b1 = (const float*)d_in[3];
    const float* W2 = (const float*)d_in[4];
    const float* b2 = (const float*)d_in[5];
    float* out = (float*)d_out;

    float* PXT    = (float*)d_ws;            // [H][NS]  1 MB (transposed)
    float* PYT    = PXT + (size_t)H * NS;    // [H][NS]  1 MB (transposed)
    float* eparts = PYT + (size_t)H * NS;    // [512]
    float* dparts = eparts + 512;            // [512]
    float* FX     = dparts + 512;            // [1024]
    float* GY     = FX + NS;                 // [1024]
    int*   counter = (int*)(GY + NS);        // [1]

    // zero FX, GY, counter (contiguous: 2048 floats + 4 bytes)
    hipMemsetAsync(FX, 0, (size_t)(2 * NS) * sizeof(float) + sizeof(int), stream);

    proj_kernel<<<dim3(8, 32, 2), 256, 0, stream>>>(X, Y, W1, b1, W2, PXT, PYT, FX, GY);
    pair_kernel<<<dim3(8, 64), 256, 0, stream>>>(PXT, PYT, W2, b2, FX, GY,
                                                 eparts, dparts, counter, out);
}

// Round 6
// 122.368 us; speedup vs baseline: 1.1673x; 1.1673x over previous
//
#include <hip/hip_runtime.h>

#define NS 1024
#define KD 256
#define H  256
#define PAIR_NBLK 512

#define GLOAD_LDS16(gp, lp)                                                         \
    __builtin_amdgcn_global_load_lds(                                               \
        (const __attribute__((address_space(1))) void*)(gp),                        \
        (__attribute__((address_space(3))) void*)(lp), 16, 0, 0)

// ---------------------------------------------------------------------------
// proj: PXT[h][j] = x_j . W1[:,h]   (transposed output, coalesced)
//       PYT[h][i] = y_i . W1[256+,h] + b1[h]
//       FX[j] = sum_h w2[h]*PXT[h][j],  GY[i] = sum_h w2[h]*PYT[h][i]
// grid (8, 32, 2), block 256.
// ---------------------------------------------------------------------------
__global__ __launch_bounds__(256) void proj_kernel(
    const float* __restrict__ X, const float* __restrict__ Y,
    const float* __restrict__ W1, const float* __restrict__ b1,
    const float* __restrict__ W2,
    float* __restrict__ PXT, float* __restrict__ PYT,
    float* __restrict__ FX, float* __restrict__ GY)
{
    const int z = blockIdx.z;
    const float* __restrict__ A = z ? Y : X;
    const float* __restrict__ W = W1 + (z ? (size_t)KD * H : 0);
    float* __restrict__ OUT = z ? PYT : PXT;
    float* __restrict__ RS  = z ? GY : FX;

    __shared__ float xs[KD][34];    // transposed [k][sample-local]
    __shared__ float fred[8][33];

    const int tid = threadIdx.x;
    const int jl = tid & 31;        // sample within block
    const int hg = tid >> 5;        // 0..7, 4 h's each
    const int i0 = blockIdx.y * 32, h0 = blockIdx.x * 32;

    // stage A rows transposed (32 rows x 256 k), once
    {
        const int ii = tid & 31, q = tid >> 5;
        #pragma unroll
        for (int u = 0; u < 8; ++u) {
            const int k = u * 32 + q * 4;
            float4 v = *(const float4*)&A[(i0 + ii) * KD + k];
            xs[k + 0][ii] = v.x; xs[k + 1][ii] = v.y;
            xs[k + 2][ii] = v.z; xs[k + 3][ii] = v.w;
        }
    }
    __syncthreads();

    float acc[4] = {};
    const float* __restrict__ wp = &W[h0 + hg * 4];
    #pragma unroll 8
    for (int k = 0; k < KD; ++k) {
        float4 w4 = *(const float4*)&wp[(size_t)k * H];
        const float xv = xs[k][jl];
        acc[0] = fmaf(xv, w4.x, acc[0]);
        acc[1] = fmaf(xv, w4.y, acc[1]);
        acc[2] = fmaf(xv, w4.z, acc[2]);
        acc[3] = fmaf(xv, w4.w, acc[3]);
    }

    if (z) {
        float4 bv = *(const float4*)&b1[h0 + hg * 4];
        acc[0] += bv.x; acc[1] += bv.y; acc[2] += bv.z; acc[3] += bv.w;
    }

    float4 w2v = *(const float4*)&W2[h0 + hg * 4];
    float fp = 0.f;
    const float w2a[4] = {w2v.x, w2v.y, w2v.z, w2v.w};
    #pragma unroll
    for (int c = 0; c < 4; ++c) {
        const int h = h0 + hg * 4 + c;
        OUT[(size_t)h * NS + i0 + jl] = acc[c];   // coalesced: 32 consecutive j
        fp = fmaf(w2a[c], acc[c], fp);
    }
    fred[hg][jl] = fp;
    __syncthreads();
    if (tid < 32) {
        float s = 0.f;
        #pragma unroll
        for (int g = 0; g < 8; ++g) s += fred[g][tid];
        atomicAdd(&RS[i0 + tid], s);
    }
}

// ---------------------------------------------------------------------------
// pair: tile 128 j x 16 i, grid (8,64)=512 blocks (2 blocks/CU, 2 waves/SIMD).
// ALL inner-loop operands from LDS:
//   px: [32][128] h-chunks, double-buffered, staged via global_load_lds.
//   py: [256][16] staged once, read as uniform-address b128 broadcast.
//   w2: [256] staged once, uniform b32 broadcast.
// inner: u = py+px; acc = fma(|u|, w2, acc)  (abs folds as VOP3 modifier).
// t1 = 0.5*(acc + FX_j + GY_i) + b2 - 1. exp-sum + diag; last block finalizes.
// ---------------------------------------------------------------------------
__global__ __launch_bounds__(256) void pair_kernel(
    const float* __restrict__ PXT, const float* __restrict__ PYT,
    const float* __restrict__ W2, const float* __restrict__ b2,
    const float* __restrict__ FX, const float* __restrict__ GY,
    float* __restrict__ eparts, float* __restrict__ dparts,
    int* __restrict__ counter, float* __restrict__ out)
{
    __shared__ float pxs[2][32][128];   // 32 KB
    __shared__ float pys[256][16];      // 16 KB, [h][i-local]
    __shared__ float w2s[H];            // 1 KB
    __shared__ float red_e[256], red_d[256];
    __shared__ double sde[256], sdd[256];
    __shared__ int lastflag;

    const int tid = threadIdx.x;
    const int lane = tid & 63;
    const int wid = __builtin_amdgcn_readfirstlane(tid >> 6);
    const int j0 = blockIdx.x * 128;
    const int i0 = blockIdx.y * 16;

#define STAGE(T, B)                                                             \
    {                                                                           \
        const float* gb = &PXT[(size_t)((T) * 32) * NS + j0];                   \
        _Pragma("unroll")                                                       \
        for (int p = 0; p < 4; ++p) {                                           \
            const int hrow = 8 * p + 2 * wid + (lane >> 5);                     \
            const float* g = gb + (size_t)hrow * NS + (lane & 31) * 4;          \
            float* l = &pxs[B][hrow][(lane & 31) * 4];                          \
            GLOAD_LDS16(g, l);                                                  \
        }                                                                       \
    }

    STAGE(0, 0);

    // stage py tile (256 h x 16 i) once + w2
    {
        const int ii = tid & 15, hb = tid >> 4;   // 16 threads per h-row
        #pragma unroll
        for (int u = 0; u < 16; ++u) {
            const int h = hb * 16 + u;
            pys[h][ii] = PYT[(size_t)h * NS + i0 + ii];
        }
        w2s[tid] = W2[tid];
    }
    __syncthreads();

    float acc[4][2] = {};

    for (int T = 0; T < 8; ++T) {
        const int B = T & 1;
        if (T < 7) STAGE(T + 1, B ^ 1);
        #pragma unroll
        for (int hh = 0; hh < 32; ++hh) {
            const int hT = T * 32 + hh;
            float2 px2 = *(const float2*)&pxs[B][hh][lane * 2];
            float4 p4  = *(const float4*)&pys[hT][wid * 4];   // uniform -> broadcast
            const float w = w2s[hT];                          // uniform -> broadcast
            const float pya[4] = {p4.x, p4.y, p4.z, p4.w};
            #pragma unroll
            for (int r = 0; r < 4; ++r) {
                acc[r][0] = fmaf(fabsf(pya[r] + px2.x), w, acc[r][0]);
                acc[r][1] = fmaf(fabsf(pya[r] + px2.y), w, acc[r][1]);
            }
        }
        __syncthreads();
    }

    // epilogue
    const float c0 = b2[0] - 1.0f;
    float2 fx2 = *(const float2*)&FX[j0 + lane * 2];
    float4 g4 = *(const float4*)&GY[i0 + wid * 4];
    const float gya[4] = {g4.x, g4.y, g4.z, g4.w};
    const float fxa[2] = {fx2.x, fx2.y};

    float esum = 0.f, dsum = 0.f;
    #pragma unroll
    for (int r = 0; r < 4; ++r) {
        const int irow = i0 + wid * 4 + r;
        #pragma unroll
        for (int c = 0; c < 2; ++c) {
            const float t1 = fmaf(0.5f, acc[r][c] + gya[r] + fxa[c], c0);
            esum += expf(t1);
            if (irow == j0 + lane * 2 + c) dsum += t1 + 1.0f;
        }
    }

    red_e[tid] = esum;
    red_d[tid] = dsum;
    __syncthreads();
    for (int s = 128; s > 0; s >>= 1) {
        if (tid < s) {
            red_e[tid] += red_e[tid + s];
            red_d[tid] += red_d[tid + s];
        }
        __syncthreads();
    }

    const int bid = blockIdx.y * gridDim.x + blockIdx.x;   // 0..511
    if (tid == 0) {
        __hip_atomic_store(&eparts[bid], red_e[0], __ATOMIC_RELAXED, __HIP_MEMORY_SCOPE_AGENT);
        __hip_atomic_store(&dparts[bid], red_d[0], __ATOMIC_RELAXED, __HIP_MEMORY_SCOPE_AGENT);
        __threadfence();
        const int prev = __hip_atomic_fetch_add(counter, 1, __ATOMIC_ACQ_REL, __HIP_MEMORY_SCOPE_AGENT);
        lastflag = (prev == PAIR_NBLK - 1);
    }
    __syncthreads();

    if (lastflag) {
        __threadfence();
        sde[tid] = (double)__hip_atomic_load(&eparts[tid], __ATOMIC_RELAXED, __HIP_MEMORY_SCOPE_AGENT)
                 + (double)__hip_atomic_load(&eparts[tid + 256], __ATOMIC_RELAXED, __HIP_MEMORY_SCOPE_AGENT);
        sdd[tid] = (double)__hip_atomic_load(&dparts[tid], __ATOMIC_RELAXED, __HIP_MEMORY_SCOPE_AGENT)
                 + (double)__hip_atomic_load(&dparts[tid + 256], __ATOMIC_RELAXED, __HIP_MEMORY_SCOPE_AGENT);
        __syncthreads();
        for (int s = 128; s > 0; s >>= 1) {
            if (tid < s) { sde[tid] += sde[tid + s]; sdd[tid] += sdd[tid + s]; }
            __syncthreads();
        }
        if (tid == 0)
            out[0] = (float)(sdd[0] / (double)NS - sde[0] / ((double)NS * (double)NS));
    }
#undef STAGE
}

// ---------------------------------------------------------------------------
extern "C" void kernel_launch(void* const* d_in, const int* in_sizes, int n_in,
                              void* d_out, int out_size, void* d_ws, size_t ws_size,
                              hipStream_t stream)
{
    const float* X  = (const float*)d_in[0];
    const float* Y  = (const float*)d_in[1];
    const float* W1 = (const float*)d_in[2];
    const float* b1 = (const float*)d_in[3];
    const float* W2 = (const float*)d_in[4];
    const float* b2 = (const float*)d_in[5];
    float* out = (float*)d_out;

    float* PXT    = (float*)d_ws;            // [H][NS]  1 MB (transposed)
    float* PYT    = PXT + (size_t)H * NS;    // [H][NS]  1 MB (transposed)
    float* eparts = PYT + (size_t)H * NS;    // [512]
    float* dparts = eparts + 512;            // [512]
    float* FX     = dparts + 512;            // [1024]
    float* GY     = FX + NS;                 // [1024]
    int*   counter = (int*)(GY + NS);        // [1]

    // zero FX, GY, counter (contiguous)
    hipMemsetAsync(FX, 0, (size_t)(2 * NS) * sizeof(float) + sizeof(int), stream);

    proj_kernel<<<dim3(8, 32, 2), 256, 0, stream>>>(X, Y, W1, b1, W2, PXT, PYT, FX, GY);
    pair_kernel<<<dim3(8, 64), 256, 0, stream>>>(PXT, PYT, W2, b2, FX, GY,
                                                 eparts, dparts, counter, out);
}